// Round 5
// baseline (5183.257 us; speedup 1.0000x reference)
//
#include <hip/hip_runtime.h>
#include <math.h>

#define NTOK 110592      // B*D*H*W = 2*6*96*96
#define NWIN 864         // 2 * 3 * 12 * 12
#define TS   15925248    // NTOK*144

typedef unsigned short u16;
typedef unsigned int   u32;

__device__ __forceinline__ float bf2f(u16 v) { return __uint_as_float(((u32)v) << 16); }
__device__ __forceinline__ u16 f2bf(float f) {
    u32 u = __float_as_uint(f);
    u32 r = u + 0x7fffu + ((u >> 16) & 1u);
    return (u16)(r >> 16);
}
__device__ __forceinline__ float wave_sum(float v) {
    #pragma unroll
    for (int o = 32; o > 0; o >>= 1) v += __shfl_xor(v, o, 64);
    return v;
}

// qkv output column (0..71: q|k|v x 24) -> row of qkvw / index into qkvb
__device__ __forceinline__ int qkv_ro(int c, int head) {
    int seg = c / 24;
    int dim = c - seg * 24;
    return seg * 144 + head * 24 + dim;
}

// windowed token index -> source spatial coords (handles roll for shifted layers)
__device__ __forceinline__ void win_to_src(int tw, int shifted, int& sb, int& sd, int& sh, int& sw) {
    int n = tw & 127;
    int win = tw >> 7;
    int ww = win % 12;
    int wh = (win / 12) % 12;
    int rest = win / 144;
    int wd = rest % 3;
    sb = rest / 3;
    int ld = n >> 6, lh = (n >> 3) & 7, lw = n & 7;
    int dr = wd * 2 + ld, hr = wh * 8 + lh, wr = ww * 8 + lw;
    if (shifted) {
        sd = (dr + 1) % 6;
        sh = (hr + 4) % 96;
        sw = (wr + 4) % 96;
    } else {
        sd = dr; sh = hr; sw = wr;
    }
}

// ---------------- diagnostics ----------------
__global__ void init_flag(int* flag) { if (threadIdx.x == 0) *flag = 99; }

__global__ __launch_bounds__(256) void scan_bf16(const u16* __restrict__ p, long n, int stage, int* flag) {
    long i = (long)blockIdx.x * 256 + threadIdx.x;
    long stride = (long)gridDim.x * 256;
    bool bad = false;
    for (; i < n; i += stride) {
        u16 v = p[i];
        if ((v & 0x7F80u) == 0x7F80u) bad = true;   // exp all-ones: inf or NaN
    }
    if (bad) atomicMin(flag, stage);
}

__global__ __launch_bounds__(256) void scan_f32(const float* __restrict__ p, long n, int stage, int* flag) {
    long i = (long)blockIdx.x * 256 + threadIdx.x;
    long stride = (long)gridDim.x * 256;
    bool bad = false;
    for (; i < n; i += stride) {
        u32 v = __float_as_uint(p[i]);
        if ((v & 0x7F800000u) == 0x7F800000u) bad = true;
    }
    if (bad) atomicMin(flag, stage);
}

__global__ void encode_flag(const int* flag, float* out) {
    if (threadIdx.x == 0 && *flag < 99) {
        out[0] = 1000.f + 100.f * (float)(*flag);
    }
}

// ---------------- conv3d(1x3x3, pad h/w=1) + bias + LN0 -> y0(f32, in d_out), f(f32) ----------------
__global__ __launch_bounds__(192) void conv_ln0_kernel(
    const float* __restrict__ x, const float* __restrict__ cw, const float* __restrict__ cb,
    const float* __restrict__ g0, const float* __restrict__ b0,
    float* __restrict__ y0, float* __restrict__ f)
{
    int pos = blockIdx.x;                     // (b,d,h,w)
    int w = pos % 96, h = (pos / 96) % 96, d = (pos / 9216) % 6, b = pos / 55296;
    __shared__ float xs[27];
    __shared__ float vals[144];
    __shared__ float red[2];
    int tid = threadIdx.x;
    if (tid < 27) {
        int kw = tid % 3, kh = (tid / 3) % 3, ci = tid / 9;
        int hh = h + kh - 1, ww2 = w + kw - 1;
        float v = 0.f;
        if (hh >= 0 && hh < 96 && ww2 >= 0 && ww2 < 96)
            v = x[((((size_t)b * 6 + d) * 3 + ci) * 96 + hh) * 96 + ww2];
        xs[tid] = v;
    }
    __syncthreads();
    if (tid < 144) {
        const float* wp = cw + tid * 27;     // conv_w[c][ci][kh][kw], contiguous 27
        float acc = cb[tid];
        #pragma unroll
        for (int j = 0; j < 27; j++) acc += wp[j] * xs[j];
        vals[tid] = acc;
    }
    __syncthreads();
    if (tid < 64) {
        float v0 = vals[tid], v1 = vals[tid + 64], v2 = (tid < 16) ? vals[tid + 128] : 0.f;
        float s  = wave_sum(v0 + v1 + v2);
        float s2 = wave_sum(v0 * v0 + v1 * v1 + v2 * v2);
        if (tid == 0) {
            float mu = s * (1.f / 144.f);
            float var = s2 * (1.f / 144.f) - mu * mu;
            red[0] = mu; red[1] = rsqrtf(fmaxf(var, 0.f) + 1e-5f);
        }
    }
    __syncthreads();
    if (tid < 144) {
        float v = (vals[tid] - red[0]) * red[1] * g0[tid] + b0[tid];
        size_t o = (size_t)pos * 144 + tid;
        y0[o] = v;
        f[o] = v;
    }
}

// ---------------- LN + gather to windowed order, bf16 out. MODE 1: no shift; MODE 2: shifted ----------------
template<int MODE>
__global__ __launch_bounds__(256) void ln_gather(
    const float* __restrict__ in, u16* __restrict__ out,
    const float* __restrict__ g, const float* __restrict__ bt)
{
    int tok = blockIdx.x * 4 + (threadIdx.x >> 6);   // wave per token
    int lane = threadIdx.x & 63;
    int b, d, h, w;
    win_to_src(tok, MODE == 2, b, d, h, w);
    int src = ((b * 6 + d) * 96 + h) * 96 + w;
    const float* row = in + (size_t)src * 144;
    float v0 = row[lane], v1 = row[lane + 64], v2 = (lane < 16) ? row[lane + 128] : 0.f;
    float s  = wave_sum(v0 + v1 + v2);
    float s2 = wave_sum(v0 * v0 + v1 * v1 + v2 * v2);
    float mu = s * (1.f / 144.f);
    float rstd = rsqrtf(fmaxf(s2 * (1.f / 144.f) - mu * mu, 0.f) + 1e-5f);
    u16* orow = out + (size_t)tok * 144;
    orow[lane]      = f2bf((v0 - mu) * rstd * g[lane]      + bt[lane]);
    orow[lane + 64] = f2bf((v1 - mu) * rstd * g[lane + 64] + bt[lane + 64]);
    if (lane < 16)
        orow[lane + 128] = f2bf((v2 - mu) * rstd * g[lane + 128] + bt[lane + 128]);
}

// ---------------- generic 64x64 GEMM (scalar memory ops; fp32 weights) ----------------
// AMODE: 0 fp32 A rows; 1 fp32 A rows + fused LN (K=144); 2 bf16 A rows.
// EPI: 0 store bf16; 1 gelu->bf16; 2 scatter-add fp32 into fres (win_to_src); 3 add fp32 into fres; 4 y0+v->bf16.
template<int AMODE, int EPI, int SHIFTED, int K, int KPAD, int NN, int WMAP, int ADDBIAS>
__global__ __launch_bounds__(256) void gemm2(
    const void* __restrict__ Asrc, const float* __restrict__ Wt, const float* __restrict__ bias,
    u16* __restrict__ outb, float* __restrict__ fres, const float* __restrict__ y0,
    const float* __restrict__ lng, const float* __restrict__ lnb,
    int a_add, int o_add, int wld, int wcol, int head)
{
    __shared__ u16 As[64 * (KPAD + 2)];
    __shared__ float Bs[16 * 68];
    int m0 = blockIdx.y * 64, n0 = blockIdx.x * 64;
    int tid = threadIdx.x;

    // ---- stage A (full K), scalar
    if (AMODE == 0) {
        const float* A = (const float*)Asrc;
        for (int idx = tid; idx < 64 * K; idx += 256) {
            int r = idx / K, k = idx - r * K;
            As[r * (KPAD + 2) + k] = f2bf(A[(size_t)(m0 + r + a_add) * K + k]);
        }
    } else if (AMODE == 2) {
        const u16* A = (const u16*)Asrc;
        for (int idx = tid; idx < 64 * K; idx += 256) {
            int r = idx / K, k = idx - r * K;
            As[r * (KPAD + 2) + k] = A[(size_t)(m0 + r + a_add) * K + k];
        }
    } else {
        int wv = tid >> 6, lane = tid & 63;
        float g0 = lng[lane], c0 = lnb[lane];
        float g1 = lng[lane + 64], c1 = lnb[lane + 64];
        float g2 = 0.f, c2 = 0.f;
        if (lane < 16) { g2 = lng[lane + 128]; c2 = lnb[lane + 128]; }
        for (int i = 0; i < 16; i++) {
            int r = wv * 16 + i;
            const float* row = (const float*)Asrc + (size_t)(m0 + r + a_add) * 144;
            float v0 = row[lane], v1 = row[lane + 64], v2 = (lane < 16) ? row[lane + 128] : 0.f;
            float s  = wave_sum(v0 + v1 + v2);
            float s2 = wave_sum(v0 * v0 + v1 * v1 + v2 * v2);
            float mu = s * (1.f / 144.f);
            float rstd = rsqrtf(fmaxf(s2 * (1.f / 144.f) - mu * mu, 0.f) + 1e-5f);
            As[r * (KPAD + 2) + lane]      = f2bf((v0 - mu) * rstd * g0 + c0);
            As[r * (KPAD + 2) + lane + 64] = f2bf((v1 - mu) * rstd * g1 + c1);
            if (lane < 16)
                As[r * (KPAD + 2) + lane + 128] = f2bf((v2 - mu) * rstd * g2 + c2);
        }
    }
    if (KPAD > K) {
        const int PADW = KPAD - K;
        for (int idx = tid; idx < 64 * PADW; idx += 256) {
            int r = idx / PADW, c = idx - r * PADW;
            As[r * (KPAD + 2) + K + c] = 0;
        }
    }
    __syncthreads();

    int tx = tid & 15, ty = tid >> 4;
    float acc[4][4] = {{0.f}};
    int bn = tid & 63, kq = tid >> 6;

    for (int k0 = 0; k0 < KPAD; k0 += 16) {
        {   // stage B slice (16 x 64 fp32), scalar loads
            int gn = n0 + bn;
            #pragma unroll
            for (int t = 0; t < 4; t++) {
                int kk = kq * 4 + t;
                float v = 0.f;
                if (gn < NN && (k0 + kk) < K) {
                    int ro = WMAP ? qkv_ro(gn, head) : gn;
                    v = Wt[(size_t)ro * wld + wcol + k0 + kk];
                }
                Bs[kk * 68 + bn] = v;
            }
        }
        __syncthreads();
        #pragma unroll
        for (int kk = 0; kk < 16; kk++) {
            float a[4], bb[4];
            #pragma unroll
            for (int i = 0; i < 4; i++) a[i] = bf2f(As[(ty * 4 + i) * (KPAD + 2) + k0 + kk]);
            #pragma unroll
            for (int j = 0; j < 4; j++) bb[j] = Bs[kk * 68 + tx * 4 + j];
            #pragma unroll
            for (int i = 0; i < 4; i++)
                #pragma unroll
                for (int j = 0; j < 4; j++) acc[i][j] += a[i] * bb[j];
        }
        __syncthreads();
    }

    #pragma unroll
    for (int i = 0; i < 4; i++) {
        int m = m0 + ty * 4 + i;
        int orow;
        if (EPI == 2) {
            int b, d, h, w;
            win_to_src(m, SHIFTED, b, d, h, w);
            orow = ((b * 6 + d) * 96 + h) * 96 + w;
        } else orow = m + o_add;
        #pragma unroll
        for (int j = 0; j < 4; j++) {
            int n = n0 + tx * 4 + j;
            if (n >= NN) continue;
            float bv = 0.f;
            if (ADDBIAS) bv = bias[WMAP ? qkv_ro(n, head) : n];
            float v = acc[i][j] + bv;
            if (EPI == 1) v = 0.5f * v * (1.f + erff(v * 0.70710678118f));
            if (EPI == 2 || EPI == 3) {
                fres[(size_t)orow * 144 + n] += v;
            } else {
                if (EPI == 4) v += y0[(size_t)orow * NN + n];
                outb[(size_t)orow * NN + n] = f2bf(v);
            }
        }
    }
}

// ---------------- per-head window attention: block per window, thread = query row ----------------
template<int SHIFTED>
__global__ __launch_bounds__(128) void attn_head(
    const u16* __restrict__ qh, const float* __restrict__ rpb, int head,
    u16* __restrict__ ah)
{
    int win = blockIdx.x, tid = threadIdx.x;
    __shared__ u16 Ks[128 * 24];
    __shared__ u16 Vs[128 * 24];
    __shared__ float bias_s[675];
    __shared__ unsigned char reg_s[128];

    const u16* row = qh + ((size_t)win * 128 + tid) * 72;
    const float scale = 0.20412414523193154f;  // 24^-0.5
    float q[24];
    #pragma unroll
    for (int d = 0; d < 24; d++) q[d] = bf2f(row[d]) * scale;
    #pragma unroll
    for (int d = 0; d < 24; d++) {
        Ks[tid * 24 + d] = row[24 + d];
        Vs[tid * 24 + d] = row[48 + d];
    }
    for (int i = tid; i < 675; i += 128) bias_s[i] = rpb[i * 6 + head];

    int ald = tid >> 6, alh = (tid >> 3) & 7, alw = tid & 7;
    if (SHIFTED) {
        int wib = win % 432;
        int wwn = wib % 12, whn = (wib / 12) % 12, wdn = wib / 144;
        int dr = wdn * 2 + ald, hr = whn * 8 + alh, wr = wwn * 8 + alw;
        int rd = (dr < 4) ? 0 : ((dr < 5) ? 1 : 2);
        int rh = (hr < 88) ? 0 : ((hr < 92) ? 1 : 2);
        int rw = (wr < 88) ? 0 : ((wr < 92) ? 1 : 2);
        reg_s[tid] = (unsigned char)(rd * 9 + rh * 3 + rw);
    }
    __syncthreads();

    int myreg = SHIFTED ? (int)reg_s[tid] : 0;
    float m = -1e30f, den = 0.f;
    float o[24];
    #pragma unroll
    for (int d = 0; d < 24; d++) o[d] = 0.f;

    for (int j = 0; j < 128; j++) {
        float s = 0.f;
        #pragma unroll
        for (int d = 0; d < 24; d++) s += q[d] * bf2f(Ks[j * 24 + d]);
        int rdi = ald - (j >> 6) + 1;
        int rhi = alh - ((j >> 3) & 7) + 7;
        int rwi = alw - (j & 7) + 7;
        s += bias_s[(rdi * 15 + rhi) * 15 + rwi];
        if (SHIFTED) s += ((int)reg_s[j] == myreg) ? 0.f : -100.f;
        float mn = fmaxf(m, s);
        float al = __expf(m - mn);
        float e  = __expf(s - mn);
        den = den * al + e;
        #pragma unroll
        for (int d = 0; d < 24; d++) o[d] = o[d] * al + e * bf2f(Vs[j * 24 + d]);
        m = mn;
    }
    float inv = 1.f / den;
    u16* arow = ah + ((size_t)win * 128 + tid) * 24;
    #pragma unroll
    for (int d = 0; d < 24; d++) arow[d] = f2bf(o[d] * inv);
}

// ---------------- final LN + transpose to (b, d, c, h, w), f32 out (squash non-finite to 500) ----------------
__global__ __launch_bounds__(256) void final_ln_out_kernel(
    const u16* __restrict__ gsrc, const float* __restrict__ g, const float* __restrict__ bt,
    float* __restrict__ out)
{
    int bh = blockIdx.x;            // (b, d, h): 0..1151
    int h = bh % 96, d = (bh / 96) % 6, b = bh / 576;
    __shared__ float tile[96][145];
    __shared__ float stat[96][2];
    const u16* src = gsrc + (size_t)bh * 96 * 144;
    for (int i = threadIdx.x; i < 96 * 144; i += blockDim.x) {
        int wt = i / 144, c = i - wt * 144;
        tile[wt][c] = bf2f(src[i]);
    }
    __syncthreads();
    if (threadIdx.x < 96) {
        int wt = threadIdx.x;
        float s = 0.f, s2 = 0.f;
        for (int c = 0; c < 144; c++) { float v = tile[wt][c]; s += v; s2 += v * v; }
        float mu = s * (1.f / 144.f);
        float var = s2 * (1.f / 144.f) - mu * mu;
        stat[wt][0] = mu;
        stat[wt][1] = rsqrtf(fmaxf(var, 0.f) + 1e-5f);
    }
    __syncthreads();
    size_t obase = ((size_t)(b * 6 + d) * 144) * 9216 + h * 96;
    for (int i = threadIdx.x; i < 96 * 144; i += blockDim.x) {
        int c = i / 96, wt = i - c * 96;
        float v = (tile[wt][c] - stat[wt][0]) * stat[wt][1] * g[c] + bt[c];
        if (!(fabsf(v) < 1e30f)) v = 500.0f;   // squash NaN/inf (diagnostic)
        out[obase + (size_t)c * 9216 + wt] = v;
    }
}

extern "C" void kernel_launch(void* const* d_in, const int* in_sizes, int n_in,
                              void* d_out, int out_size, void* d_ws, size_t ws_size,
                              hipStream_t stream) {
    const float* x     = (const float*)d_in[0];
    const float* convw = (const float*)d_in[1];
    const float* convb = (const float*)d_in[2];
    const float* ln0g  = (const float*)d_in[3];
    const float* ln0b  = (const float*)d_in[4];
    const float* n1g   = (const float*)d_in[5];
    const float* n1b   = (const float*)d_in[6];
    const float* qkvw  = (const float*)d_in[7];
    const float* qkvb  = (const float*)d_in[8];
    const float* rpb   = (const float*)d_in[9];
    const float* projw = (const float*)d_in[10];
    const float* projb = (const float*)d_in[11];
    const float* n2g   = (const float*)d_in[12];
    const float* n2b   = (const float*)d_in[13];
    const float* fc1w  = (const float*)d_in[14];
    const float* fc1b  = (const float*)d_in[15];
    const float* fc2w  = (const float*)d_in[16];
    const float* fc2b  = (const float*)d_in[17];
    const float* linw  = (const float*)d_in[18];
    const float* linb  = (const float*)d_in[19];
    const float* ln1g  = (const float*)d_in[20];
    const float* ln1b  = (const float*)d_in[21];

    // workspace: f fp32 (63.7MB) | tok bf16 (31.9MB) | qh bf16 NTOK*72 | ah bf16 NTOK*24 | flag
    float* f   = (float*)d_ws;
    u16*   tok = (u16*)((char*)d_ws + (size_t)TS * 4);
    u16*   qh  = tok + TS;
    u16*   ah  = qh + (size_t)NTOK * 72;
    int*   flag = (int*)(ah + (size_t)NTOK * 24);
    float* y0  = (float*)d_out;    // conv+LN0 output parked in d_out (TS floats) until the end

    init_flag<<<1, 64, 0, stream>>>(flag);

    conv_ln0_kernel<<<NTOK, 192, 0, stream>>>(x, convw, convb, ln0g, ln0b, y0, f);
    scan_f32<<<1024, 256, 0, stream>>>(f, (long)TS, 1, flag);

    for (int layer = 0; layer < 2; ++layer) {
        const float* qw  = qkvw + (size_t)layer * 432 * 144;
        const float* qb  = qkvb + (size_t)layer * 432;
        const float* rp  = rpb  + (size_t)layer * 675 * 6;
        const float* pw  = projw + (size_t)layer * 144 * 144;
        const float* pb  = projb + (size_t)layer * 144;
        const float* g1  = n1g + layer * 144;
        const float* b1  = n1b + layer * 144;
        const float* g2  = n2g + layer * 144;
        const float* b2  = n2b + layer * 144;
        const float* f1w = fc1w + (size_t)layer * 288 * 144;
        const float* f1b = fc1b + (size_t)layer * 288;
        const float* f2w = fc2w + (size_t)layer * 144 * 288;
        const float* f2b = fc2b + (size_t)layer * 144;
        int sb = layer * 6;   // stage base

        // LN1 + roll + window partition -> tok (windowed bf16 rows)
        if (layer == 0) ln_gather<1><<<NTOK / 4, 256, 0, stream>>>(f, tok, g1, b1);
        else            ln_gather<2><<<NTOK / 4, 256, 0, stream>>>(f, tok, g1, b1);
        scan_bf16<<<1024, 256, 0, stream>>>(tok, (long)TS, sb + 2, flag);

        for (int h = 0; h < 6; h++) {
            // qkv for head h: tok @ W_h^T -> qh (NTOK x 72)
            gemm2<2, 0, 0, 144, 144, 72, 1, 1><<<dim3(2, NTOK / 64), 256, 0, stream>>>(
                tok, qw, qb, qh, nullptr, nullptr, nullptr, nullptr, 0, 0, 144, 0, h);
            if (h == 0) scan_bf16<<<1024, 256, 0, stream>>>(qh, (long)NTOK * 72, sb + 3, flag);
            // attention for head h -> ah (NTOK x 24)
            if (layer == 0) attn_head<0><<<NWIN, 128, 0, stream>>>(qh, rp, h, ah);
            else            attn_head<1><<<NWIN, 128, 0, stream>>>(qh, rp, h, ah);
            if (h == 0) scan_bf16<<<1024, 256, 0, stream>>>(ah, (long)NTOK * 24, sb + 4, flag);
            // proj slice for head h, scatter-add into f (bias on head 0)
            if (layer == 0) {
                if (h == 0) gemm2<2, 2, 0, 24, 32, 144, 0, 1><<<dim3(3, NTOK / 64), 256, 0, stream>>>(
                    ah, pw, pb, nullptr, f, nullptr, nullptr, nullptr, 0, 0, 144, h * 24, 0);
                else        gemm2<2, 2, 0, 24, 32, 144, 0, 0><<<dim3(3, NTOK / 64), 256, 0, stream>>>(
                    ah, pw, pb, nullptr, f, nullptr, nullptr, nullptr, 0, 0, 144, h * 24, 0);
            } else {
                if (h == 0) gemm2<2, 2, 1, 24, 32, 144, 0, 1><<<dim3(3, NTOK / 64), 256, 0, stream>>>(
                    ah, pw, pb, nullptr, f, nullptr, nullptr, nullptr, 0, 0, 144, h * 24, 0);
                else        gemm2<2, 2, 1, 24, 32, 144, 0, 0><<<dim3(3, NTOK / 64), 256, 0, stream>>>(
                    ah, pw, pb, nullptr, f, nullptr, nullptr, nullptr, 0, 0, 144, h * 24, 0);
            }
        }
        scan_f32<<<1024, 256, 0, stream>>>(f, (long)TS, sb + 5, flag);

        // MLP in two half chunks (hidden lives in tok)
        for (int c = 0; c < 2; c++) {
            int mst = c * (NTOK / 2);
            gemm2<1, 1, 0, 144, 144, 288, 0, 1><<<dim3(5, NTOK / 128), 256, 0, stream>>>(
                f, f1w, f1b, tok, nullptr, nullptr, g2, b2, mst, 0, 144, 0, 0);
            if (c == 0) scan_bf16<<<1024, 256, 0, stream>>>(tok, (long)TS, sb + 6, flag);
            gemm2<2, 3, 0, 288, 288, 144, 0, 1><<<dim3(3, NTOK / 128), 256, 0, stream>>>(
                tok, f2w, f2b, nullptr, f, nullptr, nullptr, nullptr, 0, mst, 288, 0, 0);
        }
        scan_f32<<<1024, 256, 0, stream>>>(f, (long)TS, sb + 7, flag);
    }

    // final linear + conv-residual y0 -> tok (bf16, spatial rows)
    gemm2<0, 4, 0, 144, 144, 144, 0, 1><<<dim3(3, NTOK / 64), 256, 0, stream>>>(
        f, linw, linb, tok, nullptr, y0, nullptr, nullptr, 0, 0, 144, 0, 0);
    scan_bf16<<<1024, 256, 0, stream>>>(tok, (long)TS, 14, flag);

    // trailing LN + transpose to (n, d, c, h, w), fp32 out
    final_ln_out_kernel<<<2 * 6 * 96, 256, 0, stream>>>(tok, ln1g, ln1b, (float*)d_out);

    // if any stage flagged, encode first-NaN stage into out[0]: value = 1000 + 100*stage
    encode_flag<<<1, 64, 0, stream>>>(flag, (float*)d_out);
}

// Round 6
// 2087.426 us; speedup vs baseline: 2.4831x; 2.4831x over previous
//
#include <hip/hip_runtime.h>
#include <math.h>

#define NTOK 110592      // B*D*H*W = 2*6*96*96
#define NWIN 864         // 2 * 3 * 12 * 12
#define TS   15925248    // NTOK*144
#define CHTOK 36864      // NTOK/3 (chunk tokens)
#define CHWIN 288        // windows per chunk

typedef unsigned short u16;
typedef unsigned int   u32;
typedef __attribute__((ext_vector_type(8))) short short8;
typedef __attribute__((ext_vector_type(4))) float float4v;

__device__ __forceinline__ float bf2f(u16 v) { return __uint_as_float(((u32)v) << 16); }
__device__ __forceinline__ u16 f2bf(float f) {
    u32 u = __float_as_uint(f);
    u32 r = u + 0x7fffu + ((u >> 16) & 1u);
    return (u16)(r >> 16);
}
__device__ __forceinline__ void unpack2(u32 u, float& lo, float& hi) {
    lo = __uint_as_float(u << 16);
    hi = __uint_as_float(u & 0xffff0000u);
}
__device__ __forceinline__ u32 pack2(float lo, float hi) {
    return (u32)f2bf(lo) | ((u32)f2bf(hi) << 16);
}
__device__ __forceinline__ float wave_sum(float v) {
    #pragma unroll
    for (int o = 32; o > 0; o >>= 1) v += __shfl_xor(v, o, 64);
    return v;
}

// windowed token index -> source spatial coords (handles roll for shifted layers)
__device__ __forceinline__ void win_to_src(int tw, int shifted, int& sb, int& sd, int& sh, int& sw) {
    int n = tw & 127;
    int win = tw >> 7;
    int ww = win % 12;
    int wh = (win / 12) % 12;
    int rest = win / 144;
    int wd = rest % 3;
    sb = rest / 3;
    int ld = n >> 6, lh = (n >> 3) & 7, lw = n & 7;
    int dr = wd * 2 + ld, hr = wh * 8 + lh, wr = ww * 8 + lw;
    if (shifted) {
        sd = (dr + 1) % 6;
        sh = (hr + 4) % 96;
        sw = (wr + 4) % 96;
    } else {
        sd = dr; sh = hr; sw = wr;
    }
}

// ---------------- conv3d(1x3x3, pad h/w=1) + bias + LN0 -> y0(f32, in d_out), f(f32) ----------------
__global__ __launch_bounds__(192) void conv_ln0_kernel(
    const float* __restrict__ x, const float* __restrict__ cw, const float* __restrict__ cb,
    const float* __restrict__ g0, const float* __restrict__ b0,
    float* __restrict__ y0, float* __restrict__ f)
{
    int pos = blockIdx.x;                     // (b,d,h,w)
    int w = pos % 96, h = (pos / 96) % 96, d = (pos / 9216) % 6, b = pos / 55296;
    __shared__ float xs[27];
    __shared__ float vals[144];
    __shared__ float red[2];
    int tid = threadIdx.x;
    if (tid < 27) {
        int kw = tid % 3, kh = (tid / 3) % 3, ci = tid / 9;
        int hh = h + kh - 1, ww2 = w + kw - 1;
        float v = 0.f;
        if (hh >= 0 && hh < 96 && ww2 >= 0 && ww2 < 96)
            v = x[((((size_t)b * 6 + d) * 3 + ci) * 96 + hh) * 96 + ww2];
        xs[tid] = v;
    }
    __syncthreads();
    if (tid < 144) {
        const float* wp = cw + tid * 27;
        float acc = cb[tid];
        #pragma unroll
        for (int j = 0; j < 27; j++) acc += wp[j] * xs[j];
        vals[tid] = acc;
    }
    __syncthreads();
    if (tid < 64) {
        float v0 = vals[tid], v1 = vals[tid + 64], v2 = (tid < 16) ? vals[tid + 128] : 0.f;
        float s  = wave_sum(v0 + v1 + v2);
        float s2 = wave_sum(v0 * v0 + v1 * v1 + v2 * v2);
        if (tid == 0) {
            float mu = s * (1.f / 144.f);
            float var = s2 * (1.f / 144.f) - mu * mu;
            red[0] = mu; red[1] = rsqrtf(fmaxf(var, 0.f) + 1e-5f);
        }
    }
    __syncthreads();
    if (tid < 144) {
        float v = (vals[tid] - red[0]) * red[1] * g0[tid] + b0[tid];
        size_t o = (size_t)pos * 144 + tid;
        y0[o] = v;
        f[o] = v;
    }
}

// ---------------- LN per token -> bf16. MODE 0: identity; MODE 1: windowed gather; MODE 2: shifted gather ----------------
template<int MODE>
__global__ __launch_bounds__(256) void ln_gather(
    const float* __restrict__ in, u16* __restrict__ out,
    const float* __restrict__ g, const float* __restrict__ bt)
{
    int tok = blockIdx.x * 4 + (threadIdx.x >> 6);   // wave per token
    int lane = threadIdx.x & 63;
    int src;
    if (MODE == 0) src = tok;
    else {
        int b, d, h, w;
        win_to_src(tok, MODE == 2, b, d, h, w);
        src = ((b * 6 + d) * 96 + h) * 96 + w;
    }
    const float* row = in + (size_t)src * 144;
    float v0 = row[lane], v1 = row[lane + 64], v2 = (lane < 16) ? row[lane + 128] : 0.f;
    float s  = wave_sum(v0 + v1 + v2);
    float s2 = wave_sum(v0 * v0 + v1 * v1 + v2 * v2);
    float mu = s * (1.f / 144.f);
    float rstd = rsqrtf(fmaxf(s2 * (1.f / 144.f) - mu * mu, 0.f) + 1e-5f);
    u16* orow = out + (size_t)tok * 144;
    orow[lane]      = f2bf((v0 - mu) * rstd * g[lane]      + bt[lane]);
    orow[lane + 64] = f2bf((v1 - mu) * rstd * g[lane + 64] + bt[lane + 64]);
    if (lane < 16)
        orow[lane + 128] = f2bf((v2 - mu) * rstd * g[lane + 128] + bt[lane + 128]);
}

// ---------------- MFMA GEMM: C[M,N] = A[M,144] @ W[N,144]^T (+bias), tile 64x144, 192 thr / 3 waves ----------------
// AMODE: 0 fp32 A rows; 2 bf16 A rows.
// EPI: 0 store bf16; 1 gelu->bf16; 2 scatter-add fp32 into fres (win_to_src); 3 add fp32 into fres; 4 (y0+v)->bf16.
template<int AMODE, int EPI, int SHIFTED, int ADDBIAS>
__global__ __launch_bounds__(192) void mgemm(
    const void* __restrict__ Asrc, const float* __restrict__ Wt, const float* __restrict__ bias,
    u16* __restrict__ outb, float* __restrict__ fres, const float* __restrict__ y0,
    int a_add, int a_ld, int acol, int w_ld, int wcol, int o_ld, int o_add)
{
    __shared__ u16 As[64 * 152];
    __shared__ u16 Bsh[144 * 152];
    int m0 = blockIdx.y * 64, n0 = blockIdx.x * 144;
    int tid = threadIdx.x;

    // ---- stage A (64 rows x 144 k, bf16, stride 152)
    if (AMODE == 2) {
        const u32* A = (const u32*)Asrc;
        int ald2 = a_ld >> 1, ac2 = acol >> 1;
        for (int idx = tid; idx < 4608; idx += 192) {
            int r = idx / 72, kw = idx - r * 72;
            u32 v = A[(size_t)(a_add + m0 + r) * ald2 + ac2 + kw];
            *(u32*)&As[r * 152 + 2 * kw] = v;
        }
    } else {
        const float2* A = (const float2*)Asrc;
        int ald2 = a_ld >> 1, ac2 = acol >> 1;
        for (int idx = tid; idx < 4608; idx += 192) {
            int r = idx / 72, kw = idx - r * 72;
            float2 v = A[(size_t)(a_add + m0 + r) * ald2 + ac2 + kw];
            *(u32*)&As[r * 152 + 2 * kw] = pack2(v.x, v.y);
        }
    }
    // ---- stage B (144 rows x 144 k from fp32 weights)
    for (int idx = tid; idx < 10368; idx += 192) {
        int r = idx / 72, kw = idx - r * 72;
        const float* wp = &Wt[(size_t)(n0 + r) * w_ld + wcol + 2 * kw];
        *(u32*)&Bsh[r * 152 + 2 * kw] = pack2(wp[0], wp[1]);
    }
    __syncthreads();

    int wv3 = tid / 64, lane = tid & 63;
    int mrow = lane & 15, quad = lane >> 4;
    float4v acc[4][3];
    #pragma unroll
    for (int i = 0; i < 4; i++)
        #pragma unroll
        for (int j = 0; j < 3; j++) acc[i][j] = (float4v){0.f, 0.f, 0.f, 0.f};

    #pragma unroll
    for (int ks = 0; ks < 4; ks++) {
        int k0 = ks * 32;
        short8 af[4], bf[3];
        #pragma unroll
        for (int i = 0; i < 4; i++)
            af[i] = *(const short8*)&As[(i * 16 + mrow) * 152 + k0 + quad * 8];
        #pragma unroll
        for (int j = 0; j < 3; j++)
            bf[j] = *(const short8*)&Bsh[(wv3 * 48 + j * 16 + mrow) * 152 + k0 + quad * 8];
        #pragma unroll
        for (int i = 0; i < 4; i++)
            #pragma unroll
            for (int j = 0; j < 3; j++)
                acc[i][j] = __builtin_amdgcn_mfma_f32_16x16x32_bf16(af[i], bf[j], acc[i][j], 0, 0, 0);
    }
    {   // K-tail 128..143: quads 2,3 supply zeros
        short8 z8 = {0, 0, 0, 0, 0, 0, 0, 0};
        bool tl = (quad < 2);
        short8 af[4], bf[3];
        #pragma unroll
        for (int i = 0; i < 4; i++)
            af[i] = tl ? *(const short8*)&As[(i * 16 + mrow) * 152 + 128 + quad * 8] : z8;
        #pragma unroll
        for (int j = 0; j < 3; j++)
            bf[j] = tl ? *(const short8*)&Bsh[(wv3 * 48 + j * 16 + mrow) * 152 + 128 + quad * 8] : z8;
        #pragma unroll
        for (int i = 0; i < 4; i++)
            #pragma unroll
            for (int j = 0; j < 3; j++)
                acc[i][j] = __builtin_amdgcn_mfma_f32_16x16x32_bf16(af[i], bf[j], acc[i][j], 0, 0, 0);
    }

    // ---- epilogue. C/D layout: col = lane&15 (n), row = quad*4 + reg (m)
    #pragma unroll
    for (int i = 0; i < 4; i++) {
        #pragma unroll
        for (int reg = 0; reg < 4; reg++) {
            int m = m0 + i * 16 + quad * 4 + reg;
            int orow;
            if (EPI == 2) {
                int b, d, h, w;
                win_to_src(m, SHIFTED, b, d, h, w);
                orow = ((b * 6 + d) * 96 + h) * 96 + w;
            } else orow = m + o_add;
            #pragma unroll
            for (int j = 0; j < 3; j++) {
                int n = n0 + wv3 * 48 + j * 16 + mrow;
                float v = acc[i][j][reg];
                if (ADDBIAS) v += bias[n];
                if (EPI == 1) v = 0.5f * v * (1.f + erff(v * 0.70710678118f));
                if (EPI == 2 || EPI == 3) {
                    fres[(size_t)orow * 144 + n] += v;
                } else {
                    if (EPI == 4) v += y0[(size_t)orow * o_ld + n];
                    outb[(size_t)orow * o_ld + n] = f2bf(v);
                }
            }
        }
    }
}

// ---------------- window attention: block=(win,head), 256 thr, 2 thr/query split over key halves ----------------
template<int SHIFTED>
__global__ __launch_bounds__(256) void attn_fused(
    const u16* __restrict__ qkv,        // chunk-local rows x 432 bf16
    const float* __restrict__ rpb, u16* __restrict__ tok_out, int win_base)
{
    int win = blockIdx.x;               // local to chunk
    int head = blockIdx.y;
    __shared__ u32 Ku[128 * 12];
    __shared__ u32 Vu[128 * 12];
    __shared__ float bias_s[675];
    __shared__ unsigned char reg_s[128];
    int tid = threadIdx.x;

    {   // stage K (threads 0..127) and V (threads 128..255), packed u32
        int t = tid & 127;
        const u32* src = (const u32*)(qkv + ((size_t)win * 128 + t) * 432);
        int off = (tid < 128) ? (72 + 12 * head) : (144 + 12 * head);
        u32* dst = (tid < 128) ? &Ku[t * 12] : &Vu[t * 12];
        #pragma unroll
        for (int i = 0; i < 12; i++) dst[i] = src[off + i];
    }
    for (int i = tid; i < 675; i += 256) bias_s[i] = rpb[i * 6 + head];
    if (SHIFTED && tid < 128) {
        int t = tid;
        int gwin = win_base + win;
        int wib = gwin % 432;
        int wwn = wib % 12, whn = (wib / 12) % 12, wdn = wib / 144;
        int ld = t >> 6, lh = (t >> 3) & 7, lw = t & 7;
        int dr = wdn * 2 + ld, hr = whn * 8 + lh, wr = wwn * 8 + lw;
        int rd = (dr < 4) ? 0 : ((dr < 5) ? 1 : 2);
        int rh = (hr < 88) ? 0 : ((hr < 92) ? 1 : 2);
        int rw = (wr < 88) ? 0 : ((wr < 92) ? 1 : 2);
        reg_s[t] = (unsigned char)(rd * 9 + rh * 3 + rw);
    }
    __syncthreads();

    int lane = tid & 63, wv = tid >> 6;
    int arow = wv * 32 + (lane & 31);   // query row
    int kh = lane >> 5;                 // key half
    int j0 = kh * 64;

    const float scale = 0.20412414523193154f;
    float q[24];
    {
        const u32* qsrc = (const u32*)(qkv + ((size_t)win * 128 + arow) * 432) + 12 * head;
        #pragma unroll
        for (int d2 = 0; d2 < 12; d2++) {
            float lo, hi; unpack2(qsrc[d2], lo, hi);
            q[2 * d2] = lo * scale; q[2 * d2 + 1] = hi * scale;
        }
    }
    unsigned long long mbits = ~0ULL;
    if (SHIFTED) {
        int myr = reg_s[arow];
        mbits = 0;
        for (int jj = 0; jj < 64; jj++)
            if ((int)reg_s[j0 + jj] == myr) mbits |= (1ULL << jj);
    }
    int ald = arow >> 6, alh = (arow >> 3) & 7, alw = arow & 7;
    float m = -1e30f, den = 0.f;
    float o[24];
    #pragma unroll
    for (int d = 0; d < 24; d++) o[d] = 0.f;

    for (int jj = 0; jj < 64; jj++) {
        int j = j0 + jj;
        const u32* kp = &Ku[j * 12];
        float s = 0.f;
        #pragma unroll
        for (int d2 = 0; d2 < 12; d2++) {
            float lo, hi; unpack2(kp[d2], lo, hi);
            s += q[2 * d2] * lo + q[2 * d2 + 1] * hi;
        }
        int rdi = ald - (j >> 6) + 1;
        int rhi = alh - ((j >> 3) & 7) + 7;
        int rwi = alw - (j & 7) + 7;
        s += bias_s[(rdi * 15 + rhi) * 15 + rwi];
        if (SHIFTED) s += ((mbits >> jj) & 1ULL) ? 0.f : -100.f;
        float mn = fmaxf(m, s);
        float al = __expf(m - mn);
        float e  = __expf(s - mn);
        den = den * al + e;
        const u32* vp = &Vu[j * 12];
        #pragma unroll
        for (int d2 = 0; d2 < 12; d2++) {
            float lo, hi; unpack2(vp[d2], lo, hi);
            o[2 * d2]     = o[2 * d2] * al     + e * lo;
            o[2 * d2 + 1] = o[2 * d2 + 1] * al + e * hi;
        }
        m = mn;
    }
    // merge the two key halves (lanes l and l^32, same wave)
    float pm = __shfl_xor(m, 32, 64);
    float pden = __shfl_xor(den, 32, 64);
    float M = fmaxf(m, pm);
    float fs = __expf(m - M), fp = __expf(pm - M);
    float inv = 1.f / (den * fs + pden * fp);
    u32* orow = (u32*)tok_out + ((size_t)((win_base + win) * 128 + arow)) * 72 + 12 * head;
    #pragma unroll
    for (int d2 = 0; d2 < 12; d2++) {
        float p0 = __shfl_xor(o[2 * d2], 32, 64);
        float p1 = __shfl_xor(o[2 * d2 + 1], 32, 64);
        float a0 = (o[2 * d2] * fs + p0 * fp) * inv;
        float a1 = (o[2 * d2 + 1] * fs + p1 * fp) * inv;
        if (kh == 0) orow[d2] = pack2(a0, a1);
    }
}

// ---------------- final LN + transpose to (b, d, c, h, w), f32 out ----------------
__global__ __launch_bounds__(256) void final_ln_out_kernel(
    const u16* __restrict__ gsrc, const float* __restrict__ g, const float* __restrict__ bt,
    float* __restrict__ out)
{
    int bh = blockIdx.x;            // (b, d, h): 0..1151
    int h = bh % 96, d = (bh / 96) % 6, b = bh / 576;
    __shared__ float tile[96][145];
    __shared__ float stat[96][2];
    const u16* src = gsrc + (size_t)bh * 96 * 144;
    for (int i = threadIdx.x; i < 96 * 144; i += blockDim.x) {
        int wt = i / 144, c = i - wt * 144;
        tile[wt][c] = bf2f(src[i]);
    }
    __syncthreads();
    if (threadIdx.x < 96) {
        int wt = threadIdx.x;
        float s = 0.f, s2 = 0.f;
        for (int c = 0; c < 144; c++) { float v = tile[wt][c]; s += v; s2 += v * v; }
        float mu = s * (1.f / 144.f);
        float var = s2 * (1.f / 144.f) - mu * mu;
        stat[wt][0] = mu;
        stat[wt][1] = rsqrtf(fmaxf(var, 0.f) + 1e-5f);
    }
    __syncthreads();
    size_t obase = ((size_t)(b * 6 + d) * 144) * 9216 + h * 96;
    for (int i = threadIdx.x; i < 96 * 144; i += blockDim.x) {
        int c = i / 96, wt = i - c * 96;
        out[obase + (size_t)c * 9216 + wt] =
            (tile[wt][c] - stat[wt][0]) * stat[wt][1] * g[c] + bt[c];
    }
}

extern "C" void kernel_launch(void* const* d_in, const int* in_sizes, int n_in,
                              void* d_out, int out_size, void* d_ws, size_t ws_size,
                              hipStream_t stream) {
    const float* x     = (const float*)d_in[0];
    const float* convw = (const float*)d_in[1];
    const float* convb = (const float*)d_in[2];
    const float* ln0g  = (const float*)d_in[3];
    const float* ln0b  = (const float*)d_in[4];
    const float* n1g   = (const float*)d_in[5];
    const float* n1b   = (const float*)d_in[6];
    const float* qkvw  = (const float*)d_in[7];
    const float* qkvb  = (const float*)d_in[8];
    const float* rpb   = (const float*)d_in[9];
    const float* projw = (const float*)d_in[10];
    const float* projb = (const float*)d_in[11];
    const float* n2g   = (const float*)d_in[12];
    const float* n2b   = (const float*)d_in[13];
    const float* fc1w  = (const float*)d_in[14];
    const float* fc1b  = (const float*)d_in[15];
    const float* fc2w  = (const float*)d_in[16];
    const float* fc2b  = (const float*)d_in[17];
    const float* linw  = (const float*)d_in[18];
    const float* linb  = (const float*)d_in[19];
    const float* ln1g  = (const float*)d_in[20];
    const float* ln1b  = (const float*)d_in[21];

    // workspace: f fp32 (63.7MB) | tok bf16 NTOK*144 (31.85MB) | qkvbuf bf16 CHTOK*432 (31.85MB) = 127.4MB (verified safe)
    float* f      = (float*)d_ws;
    u16*   tok    = (u16*)((char*)d_ws + (size_t)TS * 4);
    u16*   qkvbuf = tok + TS;
    float* y0     = (float*)d_out;   // conv+LN0 output parked in d_out until the end

    conv_ln0_kernel<<<NTOK, 192, 0, stream>>>(x, convw, convb, ln0g, ln0b, y0, f);

    for (int layer = 0; layer < 2; ++layer) {
        const float* qw  = qkvw + (size_t)layer * 432 * 144;
        const float* qb  = qkvb + (size_t)layer * 432;
        const float* rp  = rpb  + (size_t)layer * 675 * 6;
        const float* pw  = projw + (size_t)layer * 144 * 144;
        const float* pb  = projb + (size_t)layer * 144;
        const float* g1  = n1g + layer * 144;
        const float* b1  = n1b + layer * 144;
        const float* g2  = n2g + layer * 144;
        const float* b2  = n2b + layer * 144;
        const float* f1w = fc1w + (size_t)layer * 288 * 144;
        const float* f1b = fc1b + (size_t)layer * 288;
        const float* f2w = fc2w + (size_t)layer * 144 * 288;
        const float* f2b = fc2b + (size_t)layer * 144;

        // LN1 + roll + window partition -> tok (windowed bf16 rows)
        if (layer == 0) ln_gather<1><<<NTOK / 4, 256, 0, stream>>>(f, tok, g1, b1);
        else            ln_gather<2><<<NTOK / 4, 256, 0, stream>>>(f, tok, g1, b1);

        // attention in 3 token chunks; attn output overwrites tok rows of its chunk
        for (int c = 0; c < 3; c++) {
            mgemm<2, 0, 0, 1><<<dim3(3, CHTOK / 64), 192, 0, stream>>>(
                tok, qw, qb, qkvbuf, nullptr, nullptr,
                c * CHTOK, 144, 0, 144, 0, 432, 0);
            if (layer == 0)
                attn_fused<0><<<dim3(CHWIN, 6), 256, 0, stream>>>(qkvbuf, rp, tok, c * CHWIN);
            else
                attn_fused<1><<<dim3(CHWIN, 6), 256, 0, stream>>>(qkvbuf, rp, tok, c * CHWIN);
        }

        // proj + window-reverse scatter-add into f
        if (layer == 0)
            mgemm<2, 2, 0, 1><<<dim3(1, NTOK / 64), 192, 0, stream>>>(
                tok, pw, pb, nullptr, f, nullptr, 0, 144, 0, 144, 0, 144, 0);
        else
            mgemm<2, 2, 1, 1><<<dim3(1, NTOK / 64), 192, 0, stream>>>(
                tok, pw, pb, nullptr, f, nullptr, 0, 144, 0, 144, 0, 144, 0);

        // LN2 (identity order) -> tok
        ln_gather<0><<<NTOK / 4, 256, 0, stream>>>(f, tok, g2, b2);

        // MLP in two half chunks (hidden lives in qkvbuf: 55296 x 288 bf16)
        for (int c = 0; c < 2; c++) {
            int mst = c * (NTOK / 2);
            mgemm<2, 1, 0, 1><<<dim3(2, 864), 192, 0, stream>>>(
                tok, f1w, f1b, qkvbuf, nullptr, nullptr, mst, 144, 0, 144, 0, 288, 0);
            // FC2 as two K=144 slices, both add into f (bias only on slice 0)
            mgemm<2, 3, 0, 1><<<dim3(1, 864), 192, 0, stream>>>(
                qkvbuf, f2w, f2b, nullptr, f, nullptr, 0, 288, 0, 288, 0, 144, mst);
            mgemm<2, 3, 0, 0><<<dim3(1, 864), 192, 0, stream>>>(
                qkvbuf, f2w, f2b, nullptr, f, nullptr, 0, 288, 144, 288, 144, 144, mst);
        }
    }

    // final linear + conv-residual y0 -> tok (bf16, spatial rows)
    mgemm<0, 4, 0, 1><<<dim3(1, NTOK / 64), 192, 0, stream>>>(
        f, linw, linb, tok, nullptr, y0, 0, 144, 0, 144, 0, 144, 0);

    // trailing LN + transpose to (n, d, c, h, w), fp32 out
    final_ln_out_kernel<<<2 * 6 * 96, 256, 0, stream>>>(tok, ln1g, ln1b, (float*)d_out);
}

// Round 7
// 1797.218 us; speedup vs baseline: 2.8840x; 1.1615x over previous
//
#include <hip/hip_runtime.h>
#include <math.h>

#define NTOK 110592      // B*D*H*W = 2*6*96*96
#define NWIN 864         // 2 * 3 * 12 * 12
#define TS   15925248    // NTOK*144
#define CHTOK 27648      // attention chunk tokens (4 chunks)
#define CHWIN 216        // windows per attention chunk
#define FCCH  36864      // FC chunk rows (3 chunks)

typedef unsigned short u16;
typedef unsigned int   u32;
typedef __attribute__((ext_vector_type(8))) short short8;
typedef __attribute__((ext_vector_type(4))) float float4v;

__device__ __forceinline__ float bf2f(u16 v) { return __uint_as_float(((u32)v) << 16); }
__device__ __forceinline__ u16 f2bf(float f) {
    u32 u = __float_as_uint(f);
    u32 r = u + 0x7fffu + ((u >> 16) & 1u);
    return (u16)(r >> 16);
}
__device__ __forceinline__ void unpack2(u32 u, float& lo, float& hi) {
    lo = __uint_as_float(u << 16);
    hi = __uint_as_float(u & 0xffff0000u);
}
__device__ __forceinline__ u32 pack2(float lo, float hi) {
    return (u32)f2bf(lo) | ((u32)f2bf(hi) << 16);
}
__device__ __forceinline__ float wave_sum(float v) {
    #pragma unroll
    for (int o = 32; o > 0; o >>= 1) v += __shfl_xor(v, o, 64);
    return v;
}

// windowed token index -> source spatial coords (handles roll for shifted layers)
__device__ __forceinline__ void win_to_src(int tw, int shifted, int& sb, int& sd, int& sh, int& sw) {
    int n = tw & 127;
    int win = tw >> 7;
    int ww = win % 12;
    int wh = (win / 12) % 12;
    int rest = win / 144;
    int wd = rest % 3;
    sb = rest / 3;
    int ld = n >> 6, lh = (n >> 3) & 7, lw = n & 7;
    int dr = wd * 2 + ld, hr = wh * 8 + lh, wr = ww * 8 + lw;
    if (shifted) {
        sd = (dr + 1) % 6;
        sh = (hr + 4) % 96;
        sw = (wr + 4) % 96;
    } else {
        sd = dr; sh = hr; sw = wr;
    }
}

// ---------------- weight pre-conversion fp32 -> bf16 into wbuf ----------------
// layout (u16 offsets): qkvw 0 (2x62208) | projw 124416 (2x20736) | fc1w 165888 (2x41472)
//                       | fc2w 248832 (2x41472) | linw 331776 (20736); total 352512
__global__ __launch_bounds__(256) void convert_weights(
    const float* __restrict__ qkvw, const float* __restrict__ projw,
    const float* __restrict__ fc1w, const float* __restrict__ fc2w,
    const float* __restrict__ linw, u16* __restrict__ wbuf)
{
    int i = blockIdx.x * 256 + threadIdx.x;
    if (i < 124416) wbuf[i] = f2bf(qkvw[i]);
    else if (i < 165888) wbuf[i] = f2bf(projw[i - 124416]);
    else if (i < 248832) wbuf[i] = f2bf(fc1w[i - 165888]);
    else if (i < 331776) wbuf[i] = f2bf(fc2w[i - 248832]);
    else if (i < 352512) wbuf[i] = f2bf(linw[i - 331776]);
}

// ---------------- conv3d(1x3x3) + bias + LN0, block = (b,d,h) row of 96 positions ----------------
__global__ __launch_bounds__(256) void conv_ln0_row(
    const float* __restrict__ x, const float* __restrict__ cw, const float* __restrict__ cb,
    const float* __restrict__ g0, const float* __restrict__ b0,
    float* __restrict__ y0, float* __restrict__ f)
{
    int bh = blockIdx.x;                 // (b*6+d)*96 + h
    int h = bh % 96, bd = bh / 96;
    int b = bd / 6, d = bd - b * 6;
    __shared__ float ws[192][29];        // conv weights, rows 144..191 zero; stride 29 -> 2-way free
    __shared__ float xsr[9][100];        // (ci*3+kh) x (w+pad)
    __shared__ float cbias[192], gg[144], bbv[144];
    int tid = threadIdx.x;

    for (int i = tid; i < 9 * 98; i += 256) {
        int row = i / 98, wx = i - row * 98;
        int ci = row / 3, kh = row - 3 * ci;
        int hh = h + kh - 1, wsrc = wx - 1;
        float v = 0.f;
        if (hh >= 0 && hh < 96 && wsrc >= 0 && wsrc < 96)
            v = x[((((size_t)b * 6 + d) * 3 + ci) * 96 + hh) * 96 + wsrc];
        xsr[row][wx] = v;
    }
    for (int i = tid; i < 192 * 27; i += 256) {
        int c = i / 27, j = i - c * 27;
        ws[c][j] = (c < 144) ? cw[c * 27 + j] : 0.f;
    }
    for (int i = tid; i < 192; i += 256) cbias[i] = (i < 144) ? cb[i] : 0.f;
    for (int i = tid; i < 144; i += 256) { gg[i] = g0[i]; bbv[i] = b0[i]; }
    __syncthreads();

    int wv = tid >> 6, lane = tid & 63;
    for (int p = wv; p < 96; p += 4) {
        float v0 = cbias[lane], v1 = cbias[lane + 64], v2 = cbias[lane + 128];
        #pragma unroll
        for (int j = 0; j < 27; j++) {
            int ci = j / 9, kh = (j / 3) % 3, kw = j - (j / 3) * 3;
            float xv = xsr[ci * 3 + kh][p + kw];      // wave-uniform broadcast
            v0 += ws[lane][j] * xv;
            v1 += ws[lane + 64][j] * xv;
            v2 += ws[lane + 128][j] * xv;
        }
        float v2m = (lane < 16) ? v2 : 0.f;
        float s  = wave_sum(v0 + v1 + v2m);
        float s2 = wave_sum(v0 * v0 + v1 * v1 + v2m * v2m);
        float mu = s * (1.f / 144.f);
        float rstd = rsqrtf(fmaxf(s2 * (1.f / 144.f) - mu * mu, 0.f) + 1e-5f);
        size_t o = ((size_t)bh * 96 + p) * 144;
        float r0 = (v0 - mu) * rstd * gg[lane] + bbv[lane];
        float r1 = (v1 - mu) * rstd * gg[lane + 64] + bbv[lane + 64];
        y0[o + lane] = r0;      f[o + lane] = r0;
        y0[o + lane + 64] = r1; f[o + lane + 64] = r1;
        if (lane < 16) {
            float r2 = (v2 - mu) * rstd * gg[lane + 128] + bbv[lane + 128];
            y0[o + lane + 128] = r2; f[o + lane + 128] = r2;
        }
    }
}

// ---------------- LN per token -> bf16. MODE 0: identity; MODE 1: windowed gather; MODE 2: shifted ----------------
template<int MODE>
__global__ __launch_bounds__(256) void ln_gather(
    const float* __restrict__ in, u16* __restrict__ out,
    const float* __restrict__ g, const float* __restrict__ bt)
{
    int tok = blockIdx.x * 4 + (threadIdx.x >> 6);
    int lane = threadIdx.x & 63;
    int src;
    if (MODE == 0) src = tok;
    else {
        int b, d, h, w;
        win_to_src(tok, MODE == 2, b, d, h, w);
        src = ((b * 6 + d) * 96 + h) * 96 + w;
    }
    const float* row = in + (size_t)src * 144;
    float v0 = row[lane], v1 = row[lane + 64], v2 = (lane < 16) ? row[lane + 128] : 0.f;
    float s  = wave_sum(v0 + v1 + v2);
    float s2 = wave_sum(v0 * v0 + v1 * v1 + v2 * v2);
    float mu = s * (1.f / 144.f);
    float rstd = rsqrtf(fmaxf(s2 * (1.f / 144.f) - mu * mu, 0.f) + 1e-5f);
    u16* orow = out + (size_t)tok * 144;
    orow[lane]      = f2bf((v0 - mu) * rstd * g[lane]      + bt[lane]);
    orow[lane + 64] = f2bf((v1 - mu) * rstd * g[lane + 64] + bt[lane + 64]);
    if (lane < 16)
        orow[lane + 128] = f2bf((v2 - mu) * rstd * g[lane + 128] + bt[lane + 128]);
}

// ---------------- MFMA GEMM: C[M,N] = A[M,144*KTILES] @ W^T (+bias), tile 64x144, 192 thr ----------------
// AMODE: 0 fp32 A rows; 2 bf16 A rows. Wt is bf16 (pre-converted).
// EPI: 0 store bf16; 1 gelu->bf16; 2 scatter-add f32 (win_to_src); 3 add f32; 4 (y0+v)->bf16.
template<int AMODE, int EPI, int SHIFTED, int ADDBIAS, int KTILES>
__global__ __launch_bounds__(192) void mgemm(
    const void* __restrict__ Asrc, const u16* __restrict__ Wt, const float* __restrict__ bias,
    u16* __restrict__ outb, float* __restrict__ fres, const float* __restrict__ y0,
    int a_add, int a_ld, int w_ld, int o_ld, int o_add)
{
    __shared__ u16 As[64 * 152];
    __shared__ u16 Bsh[144 * 152];
    int m0 = blockIdx.y * 64, n0 = blockIdx.x * 144;
    int tid = threadIdx.x;
    int wv3 = tid / 64, lane = tid & 63;
    int mrow = lane & 15, quad = lane >> 4;

    float4v acc[4][3];
    #pragma unroll
    for (int i = 0; i < 4; i++)
        #pragma unroll
        for (int j = 0; j < 3; j++) acc[i][j] = (float4v){0.f, 0.f, 0.f, 0.f};

    #pragma unroll
    for (int kt = 0; kt < KTILES; kt++) {
        if (kt) __syncthreads();
        // stage A (64 x 144 bf16), k-slice kt
        if (AMODE == 2) {
            const u32* A = (const u32*)Asrc;
            int ald2 = a_ld >> 1, c0 = kt * 72;
            for (int idx = tid; idx < 4608; idx += 192) {
                int r = idx / 72, kw = idx - r * 72;
                *(u32*)&As[r * 152 + 2 * kw] = A[(size_t)(a_add + m0 + r) * ald2 + c0 + kw];
            }
        } else {
            const float2* A = (const float2*)Asrc;
            int ald2 = a_ld >> 1, c0 = kt * 72;
            for (int idx = tid; idx < 4608; idx += 192) {
                int r = idx / 72, kw = idx - r * 72;
                float2 v = A[(size_t)(a_add + m0 + r) * ald2 + c0 + kw];
                *(u32*)&As[r * 152 + 2 * kw] = pack2(v.x, v.y);
            }
        }
        // stage B (144 x 144 bf16 from wbuf)
        {
            const u32* W2 = (const u32*)Wt;
            int wld2 = w_ld >> 1, c0 = kt * 72;
            for (int idx = tid; idx < 10368; idx += 192) {
                int r = idx / 72, kw = idx - r * 72;
                *(u32*)&Bsh[r * 152 + 2 * kw] = W2[(size_t)(n0 + r) * wld2 + c0 + kw];
            }
        }
        __syncthreads();

        #pragma unroll
        for (int ks = 0; ks < 4; ks++) {
            int k0 = ks * 32;
            short8 af[4], bf[3];
            #pragma unroll
            for (int i = 0; i < 4; i++)
                af[i] = *(const short8*)&As[(i * 16 + mrow) * 152 + k0 + quad * 8];
            #pragma unroll
            for (int j = 0; j < 3; j++)
                bf[j] = *(const short8*)&Bsh[(wv3 * 48 + j * 16 + mrow) * 152 + k0 + quad * 8];
            #pragma unroll
            for (int i = 0; i < 4; i++)
                #pragma unroll
                for (int j = 0; j < 3; j++)
                    acc[i][j] = __builtin_amdgcn_mfma_f32_16x16x32_bf16(af[i], bf[j], acc[i][j], 0, 0, 0);
        }
        {   // K-tail 128..143: quads 2,3 supply zeros
            short8 z8 = {0, 0, 0, 0, 0, 0, 0, 0};
            bool tl = (quad < 2);
            short8 af[4], bf[3];
            #pragma unroll
            for (int i = 0; i < 4; i++)
                af[i] = tl ? *(const short8*)&As[(i * 16 + mrow) * 152 + 128 + quad * 8] : z8;
            #pragma unroll
            for (int j = 0; j < 3; j++)
                bf[j] = tl ? *(const short8*)&Bsh[(wv3 * 48 + j * 16 + mrow) * 152 + 128 + quad * 8] : z8;
            #pragma unroll
            for (int i = 0; i < 4; i++)
                #pragma unroll
                for (int j = 0; j < 3; j++)
                    acc[i][j] = __builtin_amdgcn_mfma_f32_16x16x32_bf16(af[i], bf[j], acc[i][j], 0, 0, 0);
        }
    }

    // epilogue. C/D layout: col = lane&15 (n), row = quad*4 + reg (m)
    #pragma unroll
    for (int i = 0; i < 4; i++) {
        #pragma unroll
        for (int reg = 0; reg < 4; reg++) {
            int m = m0 + i * 16 + quad * 4 + reg;
            int orow;
            if (EPI == 2) {
                int b, d, h, w;
                win_to_src(m, SHIFTED, b, d, h, w);
                orow = ((b * 6 + d) * 96 + h) * 96 + w;
            } else orow = m + o_add;
            #pragma unroll
            for (int j = 0; j < 3; j++) {
                int n = n0 + wv3 * 48 + j * 16 + mrow;
                float v = acc[i][j][reg];
                if (ADDBIAS) v += bias[n];
                if (EPI == 1) v = 0.5f * v * (1.f + erff(v * 0.70710678118f));
                if (EPI == 2 || EPI == 3) {
                    fres[(size_t)orow * 144 + n] += v;
                } else {
                    if (EPI == 4) v += y0[(size_t)orow * o_ld + n];
                    outb[(size_t)orow * o_ld + n] = f2bf(v);
                }
            }
        }
    }
}

// ---------------- window attention: block=(win,head), 256 thr, 2 thr/query over key halves ----------------
template<int SHIFTED>
__global__ __launch_bounds__(256) void attn_fused(
    const u16* __restrict__ qkv,        // chunk-local rows x 432 bf16
    const float* __restrict__ rpb, u16* __restrict__ tok_out, int win_base)
{
    int win = blockIdx.x;
    int head = blockIdx.y;
    __shared__ float Ks[128 * 28];      // f32, stride 28 (112B, 16B-aligned)
    __shared__ float Vs[128 * 28];
    __shared__ float bias_s[675];
    __shared__ unsigned char reg_s[128];
    int tid = threadIdx.x;

    {   // threads 0..127 stage K (f32), 128..255 stage V
        int t = tid & 127;
        const u32* src = (const u32*)(qkv + ((size_t)win * 128 + t) * 432);
        int off = (tid < 128) ? (72 + 12 * head) : (144 + 12 * head);
        float* dst = (tid < 128) ? &Ks[t * 28] : &Vs[t * 28];
        #pragma unroll
        for (int i = 0; i < 12; i++) {
            float lo, hi; unpack2(src[off + i], lo, hi);
            dst[2 * i] = lo; dst[2 * i + 1] = hi;
        }
    }
    for (int i = tid; i < 675; i += 256) bias_s[i] = rpb[i * 6 + head];
    if (SHIFTED && tid < 128) {
        int t = tid;
        int gwin = win_base + win;
        int wib = gwin % 432;
        int wwn = wib % 12, whn = (wib / 12) % 12, wdn = wib / 144;
        int ld = t >> 6, lh = (t >> 3) & 7, lw = t & 7;
        int dr = wdn * 2 + ld, hr = whn * 8 + lh, wr = wwn * 8 + lw;
        int rd = (dr < 4) ? 0 : ((dr < 5) ? 1 : 2);
        int rh = (hr < 88) ? 0 : ((hr < 92) ? 1 : 2);
        int rw = (wr < 88) ? 0 : ((wr < 92) ? 1 : 2);
        reg_s[t] = (unsigned char)(rd * 9 + rh * 3 + rw);
    }
    __syncthreads();

    int lane = tid & 63, wv = tid >> 6;
    int arow = wv * 32 + (lane & 31);   // query row
    int kh = lane >> 5;                 // key half
    int j0 = kh * 64;

    const float scale = 0.20412414523193154f;
    float q[24];
    {
        const u32* qsrc = (const u32*)(qkv + ((size_t)win * 128 + arow) * 432) + 12 * head;
        #pragma unroll
        for (int d2 = 0; d2 < 12; d2++) {
            float lo, hi; unpack2(qsrc[d2], lo, hi);
            q[2 * d2] = lo * scale; q[2 * d2 + 1] = hi * scale;
        }
    }
    unsigned long long mbits = ~0ULL;
    if (SHIFTED) {
        int myr = reg_s[arow];
        mbits = 0;
        for (int jj = 0; jj < 64; jj++)
            if ((int)reg_s[j0 + jj] == myr) mbits |= (1ULL << jj);
    }
    int ald = arow >> 6, alh = (arow >> 3) & 7, alw = arow & 7;
    float m = -1e30f, den = 0.f;
    float o[24];
    #pragma unroll
    for (int d = 0; d < 24; d++) o[d] = 0.f;

    for (int jj = 0; jj < 64; jj++) {
        int j = j0 + jj;
        const float* kp = &Ks[j * 28];
        float s = 0.f;
        #pragma unroll
        for (int d = 0; d < 24; d++) s += q[d] * kp[d];
        int rdi = ald - (j >> 6) + 1;
        int rhi = alh - ((j >> 3) & 7) + 7;
        int rwi = alw - (j & 7) + 7;
        s += bias_s[(rdi * 15 + rhi) * 15 + rwi];
        if (SHIFTED) s += ((mbits >> jj) & 1ULL) ? 0.f : -100.f;
        const float* vp = &Vs[j * 28];
        if (s <= m) {               // common path: no rescale, e*v accumulate
            float e = __expf(s - m);
            den += e;
            #pragma unroll
            for (int d = 0; d < 24; d++) o[d] += e * vp[d];
        } else {                    // new max: rescale o, new term has weight 1
            float al = __expf(m - s);
            den = den * al + 1.f;
            #pragma unroll
            for (int d = 0; d < 24; d++) o[d] = o[d] * al + vp[d];
            m = s;
        }
    }
    // merge the two key halves (lanes l and l^32, same wave)
    float pm = __shfl_xor(m, 32, 64);
    float pden = __shfl_xor(den, 32, 64);
    float M = fmaxf(m, pm);
    float fs = __expf(m - M), fp = __expf(pm - M);
    float inv = 1.f / (den * fs + pden * fp);
    u32* orow = (u32*)tok_out + ((size_t)((win_base + win) * 128 + arow)) * 72 + 12 * head;
    #pragma unroll
    for (int d2 = 0; d2 < 12; d2++) {
        float p0 = __shfl_xor(o[2 * d2], 32, 64);
        float p1 = __shfl_xor(o[2 * d2 + 1], 32, 64);
        float a0 = (o[2 * d2] * fs + p0 * fp) * inv;
        float a1 = (o[2 * d2 + 1] * fs + p1 * fp) * inv;
        if (kh == 0) orow[d2] = pack2(a0, a1);
    }
}

// ---------------- final LN + transpose to (b, d, c, h, w), f32 out ----------------
__global__ __launch_bounds__(256) void final_ln_out_kernel(
    const u16* __restrict__ gsrc, const float* __restrict__ g, const float* __restrict__ bt,
    float* __restrict__ out)
{
    int bh = blockIdx.x;
    int h = bh % 96, d = (bh / 96) % 6, b = bh / 576;
    __shared__ float tile[96][145];
    __shared__ float stat[96][2];
    const u16* src = gsrc + (size_t)bh * 96 * 144;
    for (int i = threadIdx.x; i < 96 * 144; i += blockDim.x) {
        int wt = i / 144, c = i - wt * 144;
        tile[wt][c] = bf2f(src[i]);
    }
    __syncthreads();
    if (threadIdx.x < 96) {
        int wt = threadIdx.x;
        float s = 0.f, s2 = 0.f;
        for (int c = 0; c < 144; c++) { float v = tile[wt][c]; s += v; s2 += v * v; }
        float mu = s * (1.f / 144.f);
        float var = s2 * (1.f / 144.f) - mu * mu;
        stat[wt][0] = mu;
        stat[wt][1] = rsqrtf(fmaxf(var, 0.f) + 1e-5f);
    }
    __syncthreads();
    size_t obase = ((size_t)(b * 6 + d) * 144) * 9216 + h * 96;
    for (int i = threadIdx.x; i < 96 * 144; i += blockDim.x) {
        int c = i / 96, wt = i - c * 96;
        out[obase + (size_t)c * 9216 + wt] =
            (tile[wt][c] - stat[wt][0]) * stat[wt][1] * g[c] + bt[c];
    }
}

extern "C" void kernel_launch(void* const* d_in, const int* in_sizes, int n_in,
                              void* d_out, int out_size, void* d_ws, size_t ws_size,
                              hipStream_t stream) {
    const float* x     = (const float*)d_in[0];
    const float* convw = (const float*)d_in[1];
    const float* convb = (const float*)d_in[2];
    const float* ln0g  = (const float*)d_in[3];
    const float* ln0b  = (const float*)d_in[4];
    const float* n1g   = (const float*)d_in[5];
    const float* n1b   = (const float*)d_in[6];
    const float* qkvw  = (const float*)d_in[7];
    const float* qkvb  = (const float*)d_in[8];
    const float* rpb   = (const float*)d_in[9];
    const float* projw = (const float*)d_in[10];
    const float* projb = (const float*)d_in[11];
    const float* n2g   = (const float*)d_in[12];
    const float* n2b   = (const float*)d_in[13];
    const float* fc1w  = (const float*)d_in[14];
    const float* fc1b  = (const float*)d_in[15];
    const float* fc2w  = (const float*)d_in[16];
    const float* fc2b  = (const float*)d_in[17];
    const float* linw  = (const float*)d_in[18];
    const float* linb  = (const float*)d_in[19];
    const float* ln1g  = (const float*)d_in[20];
    const float* ln1b  = (const float*)d_in[21];

    // ws: f fp32 (63.7MB) | tok bf16 TS (31.85MB) | qkvbuf bf16 CHTOK*432 (23.9MB) | wbuf (0.7MB) = 120.1MB
    float* f      = (float*)d_ws;
    u16*   tok    = (u16*)((char*)d_ws + (size_t)TS * 4);
    u16*   qkvbuf = tok + TS;
    u16*   wbuf   = qkvbuf + (size_t)CHTOK * 432;
    float* y0     = (float*)d_out;   // conv+LN0 output parked in d_out until the end

    convert_weights<<<1377, 256, 0, stream>>>(qkvw, projw, fc1w, fc2w, linw, wbuf);
    conv_ln0_row<<<1152, 256, 0, stream>>>(x, convw, convb, ln0g, ln0b, y0, f);

    for (int layer = 0; layer < 2; ++layer) {
        const u16* qw  = wbuf + (size_t)layer * 62208;
        const u16* pw  = wbuf + 124416 + (size_t)layer * 20736;
        const u16* f1w = wbuf + 165888 + (size_t)layer * 41472;
        const u16* f2w = wbuf + 248832 + (size_t)layer * 41472;
        const float* qb  = qkvb + (size_t)layer * 432;
        const float* rp  = rpb  + (size_t)layer * 675 * 6;
        const float* pb  = projb + (size_t)layer * 144;
        const float* g1  = n1g + layer * 144;
        const float* b1  = n1b + layer * 144;
        const float* g2  = n2g + layer * 144;
        const float* b2  = n2b + layer * 144;
        const float* f1b = fc1b + (size_t)layer * 288;
        const float* f2b = fc2b + (size_t)layer * 144;

        // LN1 + roll + window partition -> tok (windowed bf16 rows)
        if (layer == 0) ln_gather<1><<<NTOK / 4, 256, 0, stream>>>(f, tok, g1, b1);
        else            ln_gather<2><<<NTOK / 4, 256, 0, stream>>>(f, tok, g1, b1);

        // attention in 4 token chunks; attn output overwrites tok rows of its chunk
        for (int c = 0; c < 4; c++) {
            mgemm<2, 0, 0, 1, 1><<<dim3(3, CHTOK / 64), 192, 0, stream>>>(
                tok, qw, qb, qkvbuf, nullptr, nullptr,
                c * CHTOK, 144, 144, 432, 0);
            if (layer == 0)
                attn_fused<0><<<dim3(CHWIN, 6), 256, 0, stream>>>(qkvbuf, rp, tok, c * CHWIN);
            else
                attn_fused<1><<<dim3(CHWIN, 6), 256, 0, stream>>>(qkvbuf, rp, tok, c * CHWIN);
        }

        // proj + window-reverse scatter-add into f
        if (layer == 0)
            mgemm<2, 2, 0, 1, 1><<<dim3(1, NTOK / 64), 192, 0, stream>>>(
                tok, pw, pb, nullptr, f, nullptr, 0, 144, 144, 144, 0);
        else
            mgemm<2, 2, 1, 1, 1><<<dim3(1, NTOK / 64), 192, 0, stream>>>(
                tok, pw, pb, nullptr, f, nullptr, 0, 144, 144, 144, 0);

        // LN2 (identity order) -> tok
        ln_gather<0><<<NTOK / 4, 256, 0, stream>>>(f, tok, g2, b2);

        // MLP in three chunks (hidden lives in qkvbuf: FCCH x 288 bf16)
        for (int c = 0; c < 3; c++) {
            int mst = c * FCCH;
            mgemm<2, 1, 0, 1, 1><<<dim3(2, FCCH / 64), 192, 0, stream>>>(
                tok, f1w, f1b, qkvbuf, nullptr, nullptr, mst, 144, 144, 288, 0);
            mgemm<2, 3, 0, 1, 2><<<dim3(1, FCCH / 64), 192, 0, stream>>>(
                qkvbuf, f2w, f2b, nullptr, f, nullptr, 0, 288, 288, 144, mst);
        }
    }

    // final linear + conv-residual y0 -> tok (bf16, spatial rows)
    mgemm<0, 4, 0, 1, 1><<<dim3(1, NTOK / 64), 192, 0, stream>>>(
        f, wbuf + 331776, linb, tok, nullptr, y0, 0, 144, 144, 144, 0);

    // trailing LN + transpose to (n, d, c, h, w), fp32 out
    final_ln_out_kernel<<<2 * 6 * 96, 256, 0, stream>>>(tok, ln1g, ln1b, (float*)d_out);
}